// Round 7
// baseline (228.589 us; speedup 1.0000x reference)
//
#include <hip/hip_runtime.h>
#include <hip/hip_bf16.h>
#include <math.h>

#define E_CNT 600000
#define N_CNT 50000
#define H_DIM 128
#define OE_DIM 256

typedef __attribute__((ext_vector_type(8))) short short8;
typedef __attribute__((ext_vector_type(4))) float f32x4;

// ---------------- workspace layout (bytes), total ~4 MB
#define WS_EIDS   0            // int[E]            2,400,000
#define WS_OFF    2400000      // int[N+1]
#define WS_CURS   2600008      // int[N]
#define WS_CNT    2800008      // int[N]
#define WS_WUP    3000016      // ushort[32768]
#define WS_WL1    3065552      // ushort[65536]
#define WS_WL2    3196624      // ushort[65536]
#define WS_WL3    3327696      // ushort[65536]
#define WS_TEXC   3500000      // int[50176]
#define WS_BSUM   3700704      // int[256]

#define SCAN_NB 196            // ceil(50000/256)
#define WCONV_NB 896           // 229376/256

// ---------------------------------------------------------------------------
// Fused: weight shuffle (blocks 0..895) + histogram (blocks 896..1919).
// wconv: f32 [O][K] -> bf16 MFMA b-frag order:
//   dst[((ot*KS+ks)*64+lane)*8+j] = W[ot*16+(lane&15)][ks*32+8*(lane>>4)+j]
// ---------------------------------------------------------------------------
__global__ __launch_bounds__(256) void histwconv_kernel(
    const int* __restrict__ nid, int* __restrict__ counts,
    const float* __restrict__ Wup, const float* __restrict__ Wl1,
    const float* __restrict__ Wl2, const float* __restrict__ Wl3,
    ushort* __restrict__ dUp, ushort* __restrict__ dL1,
    ushort* __restrict__ dL2, ushort* __restrict__ dL3)
{
    if (blockIdx.x < WCONV_NB) {
        int d = blockIdx.x * 256 + threadIdx.x;
        const float* W;
        ushort* dst;
        int K;
        if (d < 32768)       { W = Wup; dst = dUp; K = 128; }
        else if (d < 98304)  { d -= 32768;  W = Wl1; dst = dL1; K = 256; }
        else if (d < 163840) { d -= 98304;  W = Wl2; dst = dL2; K = 256; }
        else                 { d -= 163840; W = Wl3; dst = dL3; K = 256; }
        int j = d & 7;
        int l = (d >> 3) & 63;
        int KS = K >> 5;
        int ks = (d >> 9) % KS;
        int ot = (d >> 9) / KS;
        int k = ks * 32 + ((l >> 4) << 3) + j;
        int o = ot * 16 + (l & 15);
        __hip_bfloat16 h = __float2bfloat16(W[o * K + k]);
        dst[d] = *(const ushort*)&h;
    } else {
        int nb = gridDim.x - WCONV_NB;
        for (int e = (blockIdx.x - WCONV_NB) * 256 + threadIdx.x; e < E_CNT;
             e += nb * 256)
            atomicAdd(&counts[nid[e]], 1);
    }
}

// ---------------------------------------------------------------------------
// Coalesced scan (2 kernels) + CSR fill
// ---------------------------------------------------------------------------
__global__ __launch_bounds__(256) void scanA_kernel(const int* __restrict__ counts,
                                                    int* __restrict__ texc,
                                                    int* __restrict__ bsum)
{
    __shared__ int s[256];
    const int t = threadIdx.x;
    const int i = blockIdx.x * 256 + t;
    int v = (i < N_CNT) ? counts[i] : 0;
    s[t] = v;
    __syncthreads();
    for (int off = 1; off < 256; off <<= 1) {
        int u = (t >= off) ? s[t - off] : 0;
        __syncthreads();
        s[t] += u;
        __syncthreads();
    }
    texc[i] = s[t] - v;
    if (t == 255) bsum[blockIdx.x] = s[255];
}

// scanC: each block reduces its own prefix over bsum (196 values) -> offs
__global__ __launch_bounds__(256) void scanC_kernel(const int* __restrict__ texc,
                                                    const int* __restrict__ bsum,
                                                    int* __restrict__ offs,
                                                    int* __restrict__ cursor)
{
    __shared__ int red[256];
    const int t = threadIdx.x;
    int v = (t < (int)blockIdx.x && t < SCAN_NB) ? bsum[t] : 0;
    red[t] = v;
    __syncthreads();
    for (int off = 128; off >= 1; off >>= 1) {
        if (t < off) red[t] += red[t + off];
        __syncthreads();
    }
    const int boff = red[0];
    const int i = blockIdx.x * 256 + t;
    if (i < N_CNT) {
        int o = texc[i] + boff;
        offs[i] = o;
        cursor[i] = o;
    }
    if (i == 0) offs[N_CNT] = E_CNT;
}

__global__ __launch_bounds__(256) void fill_kernel(const int* __restrict__ nid,
                                                   int* __restrict__ cursor,
                                                   int* __restrict__ eids)
{
    for (int e = blockIdx.x * 256 + threadIdx.x; e < E_CNT; e += gridDim.x * 256) {
        int slot = atomicAdd(&cursor[nid[e]], 1);
        eids[slot] = e;
    }
}

// ---------------------------------------------------------------------------
// Fused gather + MFMA MLP. 32 nodes/block, 512 threads (8 waves), (512,4):
// cap 128 VGPR -> no spill; LDS ~37 KB -> ~3 blocks/CU at VGPR<=85.
// Gather: lane&31 owns 4 h's (float4); lane>>5 picks edge of a pair;
// depth-2 software pipeline keeps 2 x-rows in flight per half-wave.
// mfma_f32_16x16x32_bf16: a[lane l][j]=A[l&15][8*(l>>4)+j];
// D[lane l][r]=out[4*(l>>4)+r][l&15] (m89-verified).
// ---------------------------------------------------------------------------
#define MB 32
#define PITCH 264
#define EMAX 640

template<int KS, bool SW>
__device__ __forceinline__ void layer(const ushort* __restrict__ Wsh,
                                      const float* __restrict__ bias,
                                      const ushort* in_s, ushort* out_s, int tid)
{
    const int w = tid >> 6, lane = tid & 63;
    const int l15 = lane & 15, lg = lane >> 4;

    f32x4 acc[2][2];
#pragma unroll
    for (int mi = 0; mi < 2; ++mi)
#pragma unroll
        for (int oi = 0; oi < 2; ++oi)
            acc[mi][oi] = (f32x4){0.f, 0.f, 0.f, 0.f};

#pragma unroll
    for (int ks = 0; ks < KS; ++ks) {
        short8 b0 = *(const short8*)(Wsh + (size_t)(((w * 2 + 0) * KS + ks) * 64 + lane) * 8);
        short8 b1 = *(const short8*)(Wsh + (size_t)(((w * 2 + 1) * KS + ks) * 64 + lane) * 8);
#pragma unroll
        for (int mi = 0; mi < 2; ++mi) {
            short8 a = *(const short8*)(in_s + (mi * 16 + l15) * PITCH + ks * 32 + lg * 8);
            acc[mi][0] = __builtin_amdgcn_mfma_f32_16x16x32_bf16(a, b0, acc[mi][0], 0, 0, 0);
            acc[mi][1] = __builtin_amdgcn_mfma_f32_16x16x32_bf16(a, b1, acc[mi][1], 0, 0, 0);
        }
    }

#pragma unroll
    for (int oi = 0; oi < 2; ++oi) {
        float bv = bias[(w * 2 + oi) * 16 + l15];
#pragma unroll
        for (int mi = 0; mi < 2; ++mi)
#pragma unroll
            for (int r = 0; r < 4; ++r) {
                float v = acc[mi][oi][r] + bv;
                if (SW) v = v / (1.f + __expf(-v));
                __hip_bfloat16 h = __float2bfloat16(v);
                out_s[(mi * 16 + lg * 4 + r) * PITCH + (w * 2 + oi) * 16 + l15] =
                    *(const ushort*)&h;
            }
    }
}

__global__ __launch_bounds__(512, 4) void fused_kernel(
    const float* __restrict__ x, const float* __restrict__ rbf,
    const int* __restrict__ offs, const int* __restrict__ eids,
    const float* __restrict__ W_rbf, const float* __restrict__ W_w,
    const float* __restrict__ b_w,
    const ushort* __restrict__ Wup, const ushort* __restrict__ Wl1,
    const ushort* __restrict__ Wl2, const ushort* __restrict__ Wl3,
    const float* __restrict__ b_up, const float* __restrict__ b_l1,
    const float* __restrict__ b_l2, const float* __restrict__ b_l3,
    const float* __restrict__ W_out, const int* __restrict__ batch,
    float* __restrict__ out)
{
    __shared__ ushort sA[MB * PITCH];       // 16.9 KB
    __shared__ ushort sB[MB * PITCH];       // 16.9 KB
    __shared__ int s_eids[EMAX];            // 2.5 KB
    __shared__ int s_off[MB + 1];
    __shared__ float s_alpha[MB];

    const int tid = threadIdx.x;
    const int w = tid >> 6, lane = tid & 63;
    const int node0 = blockIdx.x * MB;

    // fold-in: batch -> out[N..2N)
    if (tid < MB) {
        int node = node0 + tid;
        if (node < N_CNT) out[N_CNT + node] = (float)batch[node];
    }
    if (tid < MB + 1)
        s_off[tid] = offs[min(node0 + tid, N_CNT)];
    __syncthreads();

    const int s0 = s_off[0];
    const int tot = s_off[MB] - s0;
    const int nchunks = (tot + EMAX - 1) / EMAX;   // block-uniform; ~always 1

    // ---- gather phase: wave w owns rows 4w..4w+3; chunked eids staging
    {
        const int half = lane >> 5;
        const int hb = (lane & 31) * 4;
        float wrb[4][6];
#pragma unroll
        for (int j = 0; j < 4; ++j)
#pragma unroll
            for (int k = 0; k < 6; ++k)
                wrb[j][k] = W_rbf[(hb + j) * 6 + k];
        float ww[4];
#pragma unroll
        for (int j = 0; j < 4; ++j) ww[j] = W_w[hb + j];
        const float bw = b_w[0];

        for (int c = 0; c < nchunks; ++c) {
            const int cs = c * EMAX;
            const int ce = min(cs + EMAX, tot);
            __syncthreads();                        // s_eids reuse safety
            for (int t = tid + cs; t < ce; t += 512) s_eids[t - cs] = eids[s0 + t];
            __syncthreads();

            for (int nl4 = 0; nl4 < 4; ++nl4) {
                const int nl = (w << 2) + nl4;
                const int ls = max(s_off[nl] - s0, cs);
                const int le = min(s_off[nl + 1] - s0, ce);
                float a0 = 0.f, a1 = 0.f, a2 = 0.f, a3 = 0.f;

                int i = ls;
                // depth-2 pipeline: preload pair i, then issue i+2 before FMA
                float4 xv_n = make_float4(0.f, 0.f, 0.f, 0.f);
                float2 q0n = make_float2(0.f, 0.f), q1n = q0n, q2n = q0n;
                if (i + 1 < le) {
                    const int ee = s_eids[i - cs + half];
                    xv_n = *(const float4*)(x + (size_t)ee * H_DIM + hb);
                    const float2* rp = (const float2*)(rbf + (size_t)ee * 6);
                    q0n = rp[0]; q1n = rp[1]; q2n = rp[2];
                }
                for (; i + 1 < le; ) {
                    const float4 xv = xv_n;
                    const float2 q0 = q0n, q1 = q1n, q2 = q2n;
                    i += 2;
                    if (i + 1 < le) {
                        const int ee = s_eids[i - cs + half];
                        xv_n = *(const float4*)(x + (size_t)ee * H_DIM + hb);
                        const float2* rp = (const float2*)(rbf + (size_t)ee * 6);
                        q0n = rp[0]; q1n = rp[1]; q2n = rp[2];
                    }
                    const float r[6] = {q0.x, q0.y, q1.x, q1.y, q2.x, q2.y};
                    float c0 = 0.f, c1 = 0.f, c2 = 0.f, c3 = 0.f;
#pragma unroll
                    for (int k = 0; k < 6; ++k) {
                        c0 = fmaf(r[k], wrb[0][k], c0);
                        c1 = fmaf(r[k], wrb[1][k], c1);
                        c2 = fmaf(r[k], wrb[2][k], c2);
                        c3 = fmaf(r[k], wrb[3][k], c3);
                    }
                    a0 = fmaf(c0, xv.x, a0);
                    a1 = fmaf(c1, xv.y, a1);
                    a2 = fmaf(c2, xv.z, a2);
                    a3 = fmaf(c3, xv.w, a3);
                }
                if (i < le && half == 0) {          // odd leftover edge
                    const int ee = s_eids[i - cs];
                    const float4 xv = *(const float4*)(x + (size_t)ee * H_DIM + hb);
                    const float2* rp = (const float2*)(rbf + (size_t)ee * 6);
                    const float2 q0 = rp[0], q1 = rp[1], q2 = rp[2];
                    const float r[6] = {q0.x, q0.y, q1.x, q1.y, q2.x, q2.y};
                    float c0 = 0.f, c1 = 0.f, c2 = 0.f, c3 = 0.f;
#pragma unroll
                    for (int k = 0; k < 6; ++k) {
                        c0 = fmaf(r[k], wrb[0][k], c0);
                        c1 = fmaf(r[k], wrb[1][k], c1);
                        c2 = fmaf(r[k], wrb[2][k], c2);
                        c3 = fmaf(r[k], wrb[3][k], c3);
                    }
                    a0 = fmaf(c0, xv.x, a0);
                    a1 = fmaf(c1, xv.y, a1);
                    a2 = fmaf(c2, xv.z, a2);
                    a3 = fmaf(c3, xv.w, a3);
                }

                a0 += __shfl_xor(a0, 32);
                a1 += __shfl_xor(a1, 32);
                a2 += __shfl_xor(a2, 32);
                a3 += __shfl_xor(a3, 32);

                if (half == 0) {
                    ushort4* dp = (ushort4*)(sA + nl * PITCH + hb);
                    if (c > 0) {                    // rare: accumulate partials
                        ushort4 old = *dp;
                        a0 += __bfloat162float(*(const __hip_bfloat16*)&old.x);
                        a1 += __bfloat162float(*(const __hip_bfloat16*)&old.y);
                        a2 += __bfloat162float(*(const __hip_bfloat16*)&old.z);
                        a3 += __bfloat162float(*(const __hip_bfloat16*)&old.w);
                    }
                    __hip_bfloat16 h0 = __float2bfloat16(a0), h1 = __float2bfloat16(a1);
                    __hip_bfloat16 h2 = __float2bfloat16(a2), h3 = __float2bfloat16(a3);
                    ushort4 pk;
                    pk.x = *(const ushort*)&h0;
                    pk.y = *(const ushort*)&h1;
                    pk.z = *(const ushort*)&h2;
                    pk.w = *(const ushort*)&h3;
                    *dp = pk;
                }

                float part = fmaf(a0, ww[0], fmaf(a1, ww[1], fmaf(a2, ww[2], a3 * ww[3])));
                part += __shfl_xor(part, 1);
                part += __shfl_xor(part, 2);
                part += __shfl_xor(part, 4);
                part += __shfl_xor(part, 8);
                part += __shfl_xor(part, 16);
                if (lane == 0) {
                    if (c > 0) s_alpha[nl] += part;
                    else       s_alpha[nl] = part + bw;
                }
            }
        }
    }
    __syncthreads();

    // ---- MLP phase (ping-pong, 1 barrier per layer)
    layer<4, false>(Wup, b_up, sA, sB, tid);
    __syncthreads();
    layer<8, true>(Wl1, b_l1, sB, sA, tid);
    __syncthreads();
    layer<8, true>(Wl2, b_l2, sA, sB, tid);
    __syncthreads();
    layer<8, true>(Wl3, b_l3, sB, sA, tid);
    __syncthreads();

    // out[n] = (x2[n,:] . W_out) * alpha[n]; 16 threads per node, 16 o's each
    {
        int nl = tid >> 4, q = tid & 15;
        const ushort* rowp = sA + nl * PITCH + q * 16;
        float sum = 0.f;
#pragma unroll
        for (int o = 0; o < 16; ++o) {
            __hip_bfloat16 h = *(const __hip_bfloat16*)(rowp + o);
            sum = fmaf(__bfloat162float(h), W_out[q * 16 + o], sum);
        }
        sum += __shfl_xor(sum, 1);
        sum += __shfl_xor(sum, 2);
        sum += __shfl_xor(sum, 4);
        sum += __shfl_xor(sum, 8);
        int node = node0 + nl;
        if (q == 0 && node < N_CNT) out[node] = sum * s_alpha[nl];
    }
}

extern "C" void kernel_launch(void* const* d_in, const int* in_sizes, int n_in,
                              void* d_out, int out_size, void* d_ws, size_t ws_size,
                              hipStream_t stream)
{
    const float* x      = (const float*)d_in[0];
    const float* rbf    = (const float*)d_in[1];
    const int*   nid    = (const int*)d_in[2];
    const int*   batch  = (const int*)d_in[5];
    const float* W_rbf  = (const float*)d_in[7];
    const float* W_up   = (const float*)d_in[8];
    const float* b_up   = (const float*)d_in[9];
    const float* W_l1   = (const float*)d_in[10];
    const float* b_l1   = (const float*)d_in[11];
    const float* W_l2   = (const float*)d_in[12];
    const float* b_l2   = (const float*)d_in[13];
    const float* W_l3   = (const float*)d_in[14];
    const float* b_l3   = (const float*)d_in[15];
    const float* W_out  = (const float*)d_in[16];
    const float* W_w    = (const float*)d_in[17];
    const float* b_w    = (const float*)d_in[18];

    char* ws = (char*)d_ws;
    int*    eids   = (int*)(ws + WS_EIDS);
    int*    offs   = (int*)(ws + WS_OFF);
    int*    cursor = (int*)(ws + WS_CURS);
    int*    counts = (int*)(ws + WS_CNT);
    ushort* WupS   = (ushort*)(ws + WS_WUP);
    ushort* Wl1S   = (ushort*)(ws + WS_WL1);
    ushort* Wl2S   = (ushort*)(ws + WS_WL2);
    ushort* Wl3S   = (ushort*)(ws + WS_WL3);
    int*    texc   = (int*)(ws + WS_TEXC);
    int*    bsum   = (int*)(ws + WS_BSUM);
    float*  out    = (float*)d_out;

    hipMemsetAsync(counts, 0, N_CNT * sizeof(int), stream);
    histwconv_kernel<<<WCONV_NB + 1024, 256, 0, stream>>>(
        nid, counts, W_up, W_l1, W_l2, W_l3, WupS, Wl1S, Wl2S, Wl3S);
    scanA_kernel<<<SCAN_NB, 256, 0, stream>>>(counts, texc, bsum);
    scanC_kernel<<<SCAN_NB, 256, 0, stream>>>(texc, bsum, offs, cursor);
    fill_kernel<<<1024, 256, 0, stream>>>(nid, cursor, eids);

    fused_kernel<<<(N_CNT + MB - 1) / MB, 512, 0, stream>>>(
        x, rbf, offs, eids, W_rbf, W_w, b_w,
        WupS, Wl1S, Wl2S, Wl3S, b_up, b_l1, b_l2, b_l3, W_out, batch, out);
}

// Round 8
// 219.659 us; speedup vs baseline: 1.0407x; 1.0407x over previous
//
#include <hip/hip_runtime.h>
#include <hip/hip_bf16.h>
#include <math.h>

#define E_CNT 600000
#define N_CNT 50000
#define H_DIM 128
#define OE_DIM 256

typedef __attribute__((ext_vector_type(8))) short short8;
typedef __attribute__((ext_vector_type(4))) float f32x4;

// ---------------- workspace layout (bytes), total ~154.9 MB
#define WS_OFF    0            // int[N+1]           200,004
#define WS_CURS   200008       // int[N]             200,000
#define WS_CNT    400008       // int[N]             200,000
#define WS_TEXC   600008       // int[50176]         200,704
#define WS_BSUM   800712       // int[256]             1,024
#define WS_WUP    801736       // ushort[32768]       65,536
#define WS_WL1    867272       // ushort[65536]      131,072
#define WS_WL2    998344       // ushort[65536]      131,072
#define WS_WL3    1129416      // ushort[65536]      131,072
#define WS_XE     1261568      // ushort[E*128]  153,600,000  (CSR-permuted edge features)

#define SCAN_NB 196            // ceil(50000/256)
#define WCONV_NB 896           // 229376/256

// ---------------------------------------------------------------------------
// Fused: weight shuffle (blocks 0..895) + histogram (blocks 896..1919).
// wconv: f32 [O][K] -> bf16 MFMA b-frag order:
//   dst[((ot*KS+ks)*64+lane)*8+j] = W[ot*16+(lane&15)][ks*32+8*(lane>>4)+j]
// ---------------------------------------------------------------------------
__global__ __launch_bounds__(256) void histwconv_kernel(
    const int* __restrict__ nid, int* __restrict__ counts,
    const float* __restrict__ Wup, const float* __restrict__ Wl1,
    const float* __restrict__ Wl2, const float* __restrict__ Wl3,
    ushort* __restrict__ dUp, ushort* __restrict__ dL1,
    ushort* __restrict__ dL2, ushort* __restrict__ dL3)
{
    if (blockIdx.x < WCONV_NB) {
        int d = blockIdx.x * 256 + threadIdx.x;
        const float* W;
        ushort* dst;
        int K;
        if (d < 32768)       { W = Wup; dst = dUp; K = 128; }
        else if (d < 98304)  { d -= 32768;  W = Wl1; dst = dL1; K = 256; }
        else if (d < 163840) { d -= 98304;  W = Wl2; dst = dL2; K = 256; }
        else                 { d -= 163840; W = Wl3; dst = dL3; K = 256; }
        int j = d & 7;
        int l = (d >> 3) & 63;
        int KS = K >> 5;
        int ks = (d >> 9) % KS;
        int ot = (d >> 9) / KS;
        int k = ks * 32 + ((l >> 4) << 3) + j;
        int o = ot * 16 + (l & 15);
        __hip_bfloat16 h = __float2bfloat16(W[o * K + k]);
        dst[d] = *(const ushort*)&h;
    } else {
        int nb = gridDim.x - WCONV_NB;
        for (int e = (blockIdx.x - WCONV_NB) * 256 + threadIdx.x; e < E_CNT;
             e += nb * 256)
            atomicAdd(&counts[nid[e]], 1);
    }
}

// ---------------------------------------------------------------------------
// Coalesced scan (2 kernels): texc (within-tile) then +block prefix
// ---------------------------------------------------------------------------
__global__ __launch_bounds__(256) void scanA_kernel(const int* __restrict__ counts,
                                                    int* __restrict__ texc,
                                                    int* __restrict__ bsum)
{
    __shared__ int s[256];
    const int t = threadIdx.x;
    const int i = blockIdx.x * 256 + t;
    int v = (i < N_CNT) ? counts[i] : 0;
    s[t] = v;
    __syncthreads();
    for (int off = 1; off < 256; off <<= 1) {
        int u = (t >= off) ? s[t - off] : 0;
        __syncthreads();
        s[t] += u;
        __syncthreads();
    }
    texc[i] = s[t] - v;
    if (t == 255) bsum[blockIdx.x] = s[255];
}

__global__ __launch_bounds__(256) void scanC_kernel(const int* __restrict__ texc,
                                                    const int* __restrict__ bsum,
                                                    int* __restrict__ offs,
                                                    int* __restrict__ cursor)
{
    __shared__ int red[256];
    const int t = threadIdx.x;
    int v = (t < (int)blockIdx.x && t < SCAN_NB) ? bsum[t] : 0;
    red[t] = v;
    __syncthreads();
    for (int off = 128; off >= 1; off >>= 1) {
        if (t < off) red[t] += red[t + off];
        __syncthreads();
    }
    const int boff = red[0];
    const int i = blockIdx.x * 256 + t;
    if (i < N_CNT) {
        int o = texc[i] + boff;
        offs[i] = o;
        cursor[i] = o;
    }
    if (i == 0) offs[N_CNT] = E_CNT;
}

// ---------------------------------------------------------------------------
// Prepass: streaming over edges (seq reads), compute full edge feature
// xe[h] = (rbf[e].W_rbf[h,:]) * x[e,h], allocate CSR slot via atomic, and
// scatter-write the bf16 row (256 B) to xep[slot]. Random writes are posted
// -> no latency chain; kernel runs at streaming-read BW.
// Wave = 2 edges x 32 lanes; lane owns 4 h's.
// ---------------------------------------------------------------------------
__global__ __launch_bounds__(256, 4) void prepass_kernel(
    const float* __restrict__ x, const float* __restrict__ rbf,
    const int* __restrict__ nid, int* __restrict__ cursor,
    const float* __restrict__ W_rbf,
    ushort* __restrict__ xep)
{
    const int tid = threadIdx.x;
    const int lane = tid & 63;
    const int half = lane >> 5;
    const int l31 = lane & 31;
    const int h0 = l31 * 4;

    float wrb[4][6];
#pragma unroll
    for (int j = 0; j < 4; ++j)
#pragma unroll
        for (int k = 0; k < 6; ++k)
            wrb[j][k] = W_rbf[(h0 + j) * 6 + k];

    const int wid = (blockIdx.x * 256 + tid) >> 6;
    const int nw = (gridDim.x * 256) >> 6;
    const int npair = E_CNT / 2;           // E even

    for (int p = wid; p < npair; p += nw) {
        const int e = p * 2 + half;
        const int node = nid[e];
        int slot = 0;
        if (l31 == 0) slot = atomicAdd(&cursor[node], 1);
        slot = __shfl(slot, half << 5);

        const float4 xv = *(const float4*)(x + (size_t)e * H_DIM + h0);
        const float2* rp = (const float2*)(rbf + (size_t)e * 6);
        const float2 q0 = rp[0], q1 = rp[1], q2 = rp[2];
        const float r[6] = {q0.x, q0.y, q1.x, q1.y, q2.x, q2.y};
        float c0 = 0.f, c1 = 0.f, c2 = 0.f, c3 = 0.f;
#pragma unroll
        for (int k = 0; k < 6; ++k) {
            c0 = fmaf(r[k], wrb[0][k], c0);
            c1 = fmaf(r[k], wrb[1][k], c1);
            c2 = fmaf(r[k], wrb[2][k], c2);
            c3 = fmaf(r[k], wrb[3][k], c3);
        }
        const float v0 = c0 * xv.x, v1 = c1 * xv.y, v2 = c2 * xv.z, v3 = c3 * xv.w;
        __hip_bfloat16 b0 = __float2bfloat16(v0), b1 = __float2bfloat16(v1);
        __hip_bfloat16 b2 = __float2bfloat16(v2), b3 = __float2bfloat16(v3);
        ushort4 pk;
        pk.x = *(const ushort*)&b0;
        pk.y = *(const ushort*)&b1;
        pk.z = *(const ushort*)&b2;
        pk.w = *(const ushort*)&b3;
        *(ushort4*)(xep + (size_t)slot * H_DIM + h0) = pk;
    }
}

// ---------------------------------------------------------------------------
// Fused seq-gather + MFMA MLP. 32 nodes/block, 512 threads (8 waves).
// Gather: wave w owns nodes 4w..4w+3; its slots are CONTIGUOUS in xep ->
// lane = 16*eq + p reads slot (s+eq), bytes [p*16, p*16+16) -> 1KB/instr
// coalesced, addresses affine in s (no load chain). Reduce across eq via
// shfl_xor(16/32); alpha from acc . W_w. Then ping-pong MFMA MLP (R7 layer).
// mfma_f32_16x16x32_bf16: a[lane l][j]=A[l&15][8*(l>>4)+j];
// D[lane l][r]=out[4*(l>>4)+r][l&15] (m89-verified).
// ---------------------------------------------------------------------------
#define MB 32
#define PITCH 264

template<int KS, bool SW>
__device__ __forceinline__ void layer(const ushort* __restrict__ Wsh,
                                      const float* __restrict__ bias,
                                      const ushort* in_s, ushort* out_s, int tid)
{
    const int w = tid >> 6, lane = tid & 63;
    const int l15 = lane & 15, lg = lane >> 4;

    f32x4 acc[2][2];
#pragma unroll
    for (int mi = 0; mi < 2; ++mi)
#pragma unroll
        for (int oi = 0; oi < 2; ++oi)
            acc[mi][oi] = (f32x4){0.f, 0.f, 0.f, 0.f};

#pragma unroll
    for (int ks = 0; ks < KS; ++ks) {
        short8 b0 = *(const short8*)(Wsh + (size_t)(((w * 2 + 0) * KS + ks) * 64 + lane) * 8);
        short8 b1 = *(const short8*)(Wsh + (size_t)(((w * 2 + 1) * KS + ks) * 64 + lane) * 8);
#pragma unroll
        for (int mi = 0; mi < 2; ++mi) {
            short8 a = *(const short8*)(in_s + (mi * 16 + l15) * PITCH + ks * 32 + lg * 8);
            acc[mi][0] = __builtin_amdgcn_mfma_f32_16x16x32_bf16(a, b0, acc[mi][0], 0, 0, 0);
            acc[mi][1] = __builtin_amdgcn_mfma_f32_16x16x32_bf16(a, b1, acc[mi][1], 0, 0, 0);
        }
    }

#pragma unroll
    for (int oi = 0; oi < 2; ++oi) {
        float bv = bias[(w * 2 + oi) * 16 + l15];
#pragma unroll
        for (int mi = 0; mi < 2; ++mi)
#pragma unroll
            for (int r = 0; r < 4; ++r) {
                float v = acc[mi][oi][r] + bv;
                if (SW) v = v / (1.f + __expf(-v));
                __hip_bfloat16 h = __float2bfloat16(v);
                out_s[(mi * 16 + lg * 4 + r) * PITCH + (w * 2 + oi) * 16 + l15] =
                    *(const ushort*)&h;
            }
    }
}

__global__ __launch_bounds__(512, 6) void fused_kernel(
    const ushort* __restrict__ xep,
    const int* __restrict__ offs,
    const float* __restrict__ W_w, const float* __restrict__ b_w,
    const ushort* __restrict__ Wup, const ushort* __restrict__ Wl1,
    const ushort* __restrict__ Wl2, const ushort* __restrict__ Wl3,
    const float* __restrict__ b_up, const float* __restrict__ b_l1,
    const float* __restrict__ b_l2, const float* __restrict__ b_l3,
    const float* __restrict__ W_out, const int* __restrict__ batch,
    float* __restrict__ out)
{
    __shared__ ushort sA[MB * PITCH];       // 16.9 KB
    __shared__ ushort sB[MB * PITCH];       // 16.9 KB
    __shared__ int s_off[MB + 1];
    __shared__ float s_alpha[MB];

    const int tid = threadIdx.x;
    const int w = tid >> 6, lane = tid & 63;
    const int node0 = blockIdx.x * MB;

    // fold-in: batch -> out[N..2N)
    if (tid < MB) {
        int node = node0 + tid;
        if (node < N_CNT) out[N_CNT + node] = (float)batch[node];
    }
    if (tid < MB + 1)
        s_off[tid] = offs[min(node0 + tid, N_CNT)];
    __syncthreads();

    // ---- gather phase: wave w owns nodes 4w..4w+3; sequential slot reads
    {
        const int eq = lane >> 4;           // slot offset within quad
        const int p = lane & 15;            // 8-h segment
        float ww[8];
#pragma unroll
        for (int j = 0; j < 8; ++j) ww[j] = W_w[p * 8 + j];
        const float bw = b_w[0];

        for (int nl4 = 0; nl4 < 4; ++nl4) {
            const int nl = (w << 2) + nl4;
            const int ls = s_off[nl], le = s_off[nl + 1];
            float acc[8];
#pragma unroll
            for (int j = 0; j < 8; ++j) acc[j] = 0.f;

#pragma unroll 2
            for (int s = ls + eq; s < le; s += 4) {
                short8 rv = *(const short8*)(xep + (size_t)s * H_DIM + p * 8);
#pragma unroll
                for (int j = 0; j < 8; ++j) {
                    ushort u = (ushort)rv[j];
                    acc[j] += __bfloat162float(*(const __hip_bfloat16*)&u);
                }
            }
            // reduce across the 4 slot groups
#pragma unroll
            for (int j = 0; j < 8; ++j) {
                acc[j] += __shfl_xor(acc[j], 16);
                acc[j] += __shfl_xor(acc[j], 32);
            }
            // alpha
            float part = 0.f;
#pragma unroll
            for (int j = 0; j < 8; ++j) part = fmaf(acc[j], ww[j], part);
            part += __shfl_xor(part, 1);
            part += __shfl_xor(part, 2);
            part += __shfl_xor(part, 4);
            part += __shfl_xor(part, 8);
            if (lane == 0) s_alpha[nl] = part + bw;
            // write row (bf16) into MFMA A-tile
            if (eq == 0) {
                ushort pk[8];
#pragma unroll
                for (int j = 0; j < 8; ++j) {
                    __hip_bfloat16 h = __float2bfloat16(acc[j]);
                    pk[j] = *(const ushort*)&h;
                }
                *(int4*)(sA + nl * PITCH + p * 8) = *(const int4*)pk;
            }
        }
    }
    __syncthreads();

    // ---- MLP phase (ping-pong, 1 barrier per layer)
    layer<4, false>(Wup, b_up, sA, sB, tid);
    __syncthreads();
    layer<8, true>(Wl1, b_l1, sB, sA, tid);
    __syncthreads();
    layer<8, true>(Wl2, b_l2, sA, sB, tid);
    __syncthreads();
    layer<8, true>(Wl3, b_l3, sB, sA, tid);
    __syncthreads();

    // out[n] = (x2[n,:] . W_out) * alpha[n]; 16 threads per node, 16 o's each
    {
        int nl = tid >> 4, q = tid & 15;
        const ushort* rowp = sA + nl * PITCH + q * 16;
        float sum = 0.f;
#pragma unroll
        for (int o = 0; o < 16; ++o) {
            __hip_bfloat16 h = *(const __hip_bfloat16*)(rowp + o);
            sum = fmaf(__bfloat162float(h), W_out[q * 16 + o], sum);
        }
        sum += __shfl_xor(sum, 1);
        sum += __shfl_xor(sum, 2);
        sum += __shfl_xor(sum, 4);
        sum += __shfl_xor(sum, 8);
        int node = node0 + nl;
        if (q == 0 && node < N_CNT) out[node] = sum * s_alpha[nl];
    }
}

extern "C" void kernel_launch(void* const* d_in, const int* in_sizes, int n_in,
                              void* d_out, int out_size, void* d_ws, size_t ws_size,
                              hipStream_t stream)
{
    const float* x      = (const float*)d_in[0];
    const float* rbf    = (const float*)d_in[1];
    const int*   nid    = (const int*)d_in[2];
    const int*   batch  = (const int*)d_in[5];
    const float* W_rbf  = (const float*)d_in[7];
    const float* W_up   = (const float*)d_in[8];
    const float* b_up   = (const float*)d_in[9];
    const float* W_l1   = (const float*)d_in[10];
    const float* b_l1   = (const float*)d_in[11];
    const float* W_l2   = (const float*)d_in[12];
    const float* b_l2   = (const float*)d_in[13];
    const float* W_l3   = (const float*)d_in[14];
    const float* b_l3   = (const float*)d_in[15];
    const float* W_out  = (const float*)d_in[16];
    const float* W_w    = (const float*)d_in[17];
    const float* b_w    = (const float*)d_in[18];

    char* ws = (char*)d_ws;
    int*    offs   = (int*)(ws + WS_OFF);
    int*    cursor = (int*)(ws + WS_CURS);
    int*    counts = (int*)(ws + WS_CNT);
    int*    texc   = (int*)(ws + WS_TEXC);
    int*    bsum   = (int*)(ws + WS_BSUM);
    ushort* WupS   = (ushort*)(ws + WS_WUP);
    ushort* Wl1S   = (ushort*)(ws + WS_WL1);
    ushort* Wl2S   = (ushort*)(ws + WS_WL2);
    ushort* Wl3S   = (ushort*)(ws + WS_WL3);
    ushort* xep    = (ushort*)(ws + WS_XE);
    float*  out    = (float*)d_out;

    hipMemsetAsync(counts, 0, N_CNT * sizeof(int), stream);
    histwconv_kernel<<<WCONV_NB + 1024, 256, 0, stream>>>(
        nid, counts, W_up, W_l1, W_l2, W_l3, WupS, Wl1S, Wl2S, Wl3S);
    scanA_kernel<<<SCAN_NB, 256, 0, stream>>>(counts, texc, bsum);
    scanC_kernel<<<SCAN_NB, 256, 0, stream>>>(texc, bsum, offs, cursor);

    prepass_kernel<<<2048, 256, 0, stream>>>(x, rbf, nid, cursor, W_rbf, xep);

    fused_kernel<<<(N_CNT + MB - 1) / MB, 512, 0, stream>>>(
        xep, offs, W_w, b_w,
        WupS, Wl1S, Wl2S, Wl3S, b_up, b_l1, b_l2, b_l3, W_out, batch, out);
}